// Round 14
// baseline (23.985 us; speedup 1.0000x reference)
//
#include <hip/hip_runtime.h>

#define NPTS 524288
#define HID 100
#define BLK 256
#define PPT 2
// Trans-pipe experiment: R10 was (model-fit) trans-bound — 4 trans/pair-j
// (2 exp + 2 rcp) at ~16cy wave64 => 10.7us/SIMD. This kernel cuts trans to
// 2/pair-j: t = exp2(-|y|) (neg-abs = free input modifier), then
// 1/(1+t) via the R9-validated degree-5 poly; sign restored by XOR (odd fn).
// Per pair-j: 13 pk-VALU + 4 sign ops + 2 trans.  16 waves/CU (PPT=2).
// Table: one float4/j {cx,cy,cz,gj}: cx=C*w1x, cy=C*w1y, cz=C*b1,
// gj=(2/C)*W2*(w1x-w1y), C=2log2e; u += s*gj*cy, v -= s*gj*cx.

typedef float v2f __attribute__((ext_vector_type(2)));

#if __has_builtin(__builtin_elementwise_fma)
#define VFMA(a, b, c) __builtin_elementwise_fma((a), (b), (c))
#else
#define VFMA(a, b, c) ((a) * (b) + (c))
#endif

__device__ __forceinline__ float sgnxor(float s, float y) {
    return __int_as_float(__float_as_int(s) ^
                          (__float_as_int(y) & 0x80000000));
}

__global__ void __launch_bounds__(BLK)
kDivFree_main(const float2* __restrict__ xy,
              const float* __restrict__ W1,
              const float* __restrict__ b1,
              const float* __restrict__ W2,
              float2* __restrict__ out) {
    __shared__ float4 sA[HID];   // {cx, cy, cz, gj}  1600 B

    int t = threadIdx.x;
    if (t < HID) {
        const float C = 2.8853900817779268f;   // 2*log2(e)
        float w1x = W1[t], w1y = W1[HID + t], w2 = W2[t];
        sA[t] = make_float4(w1x * C, w1y * C, b1[t] * C,
                            (2.0f / C) * w2 * (w1x - w1y));
    }
    __syncthreads();

    int base = blockIdx.x * (BLK * PPT) + threadIdx.x;
    float2 q0 = xy[base];
    float2 q1 = xy[base + BLK];
    v2f px = {q0.x, q1.x}, py = {q0.y, q1.y};
    v2f u = 0.0f, v = 0.0f;
    const v2f mone = -1.0f;
    // 1/(1+t) on t in [0,1], degree-5 minimax (validated in R9)
    const v2f c0 = 0.99996f, c1 = -0.99662f, c2 = 0.95607f,
              c3 = -0.77778f, c4 = 0.42599f, c5 = -0.10765f;

#pragma unroll 10
    for (int j = 0; j < HID; ++j) {
        float4 A = sA[j];
        v2f ax = A.x, ay = A.y, az = A.z, gj = A.w;
        v2f y = VFMA(px, ax, VFMA(py, ay, az));       // 2log2e * a
        v2f tt;
        tt.x = __builtin_amdgcn_exp2f(-__builtin_fabsf(y.x));  // e^{-2|a|}
        tt.y = __builtin_amdgcn_exp2f(-__builtin_fabsf(y.y));
        v2f g = VFMA(tt, VFMA(tt, VFMA(tt, VFMA(tt, VFMA(tt,
                c5, c4), c3), c2), c1), c0);          // ~1/(1+t)
        v2f h  = VFMA(-tt, g, g);                     // tanh(|a|) = (1-t)g
        v2f s  = h * VFMA(h, h, mone);                // s(|a|) = h^3-h <= 0
        v2f m  = s * gj;
        m.x = sgnxor(m.x, y.x);                       // odd: restore sign
        m.y = sgnxor(m.y, y.y);
        u = VFMA(m, ay, u);                           // += s*ku (ku = gj*cy)
        v = VFMA(m, -ax, v);                          // += s*kv (kv = -gj*cx)
    }

    out[base]       = make_float2(u.x, v.x);
    out[base + BLK] = make_float2(u.y, v.y);
}

extern "C" void kernel_launch(void* const* d_in, const int* in_sizes, int n_in,
                              void* d_out, int out_size, void* d_ws, size_t ws_size,
                              hipStream_t stream) {
    // inputs: 0=f (unused), 1=xy, 2=W1, 3=b1, 4=W2, 5=b2 (unused by Hessian)
    const float* xy = (const float*)d_in[1];
    const float* W1 = (const float*)d_in[2];
    const float* b1 = (const float*)d_in[3];
    const float* W2 = (const float*)d_in[4];

    kDivFree_main<<<NPTS / (BLK * PPT), BLK, 0, stream>>>(
        (const float2*)xy, W1, b1, W2, (float2*)d_out);
}

// Round 15
// 19.942 us; speedup vs baseline: 1.2027x; 1.2027x over previous
//
#include <hip/hip_runtime.h>

#define NPTS 524288
#define HID 100
#define BLK 256
#define PPT 4
// ILP experiment: R10 (8pk+4T per pair, 1 chain/wave) fits dur = C(~12us) +
// SUM(VALU 2.7us + trans 5.3us) — pipes not overlapping. This kernel runs TWO
// independent packed pairs per thread, stage-interleaved, so trans ops of one
// chain can issue under the other chain's VALU ops. If trans/VALU overlap:
// kernel term -> max(...) ~ 5.3us => ~17us total. If sum is fundamental:
// neutral ~20 => R10-class is the issue floor and C dominates (ROOFLINE).
// Table (R10's): sA[j]={cx,cy,cz,ku}, sKv[j]=kv; cx=C*w1x etc, C=2log2e,
// ku=2*W2*w1y*(w1x-w1y), kv=2*W2*w1x*(w1y-w1x). s=h^3-h, h=tanh=1-2/(1+e^{2a}).

typedef float v2f __attribute__((ext_vector_type(2)));

#if __has_builtin(__builtin_elementwise_fma)
#define VFMA(a, b, c) __builtin_elementwise_fma((a), (b), (c))
#else
#define VFMA(a, b, c) ((a) * (b) + (c))
#endif

__global__ void __launch_bounds__(BLK)
kDivFree_main(const float2* __restrict__ xy,
              const float* __restrict__ W1,
              const float* __restrict__ b1,
              const float* __restrict__ W2,
              float2* __restrict__ out) {
    __shared__ float4 sA[HID];    // {cx, cy, cz, ku}  1600 B
    __shared__ float  sKv[HID];   // kv                 400 B

    int t = threadIdx.x;
    if (t < HID) {
        const float C = 2.8853900817779268f;   // 2*log2(e)
        float w1x = W1[t], w1y = W1[HID + t], w2 = W2[t];
        sA[t] = make_float4(w1x * C, w1y * C, b1[t] * C,
                            2.0f * w2 * w1y * (w1x - w1y));
        sKv[t] = 2.0f * w2 * w1x * (w1y - w1x);
    }
    __syncthreads();

    const float4* sK4 = (const float4*)sKv;

    int base = blockIdx.x * (BLK * PPT) + threadIdx.x;
    float2 q0 = xy[base];
    float2 q1 = xy[base + BLK];
    float2 q2 = xy[base + 2 * BLK];
    float2 q3 = xy[base + 3 * BLK];
    v2f pxA = {q0.x, q1.x}, pyA = {q0.y, q1.y};
    v2f pxB = {q2.x, q3.x}, pyB = {q2.y, q3.y};
    v2f uA = 0.0f, vA = 0.0f, uB = 0.0f, vB = 0.0f;
    const v2f one = 1.0f, mtwo = -2.0f, mone = -1.0f;

#pragma unroll 5
    for (int j4 = 0; j4 < HID / 4; ++j4) {
        float4 K = sK4[j4];
        float kva[4] = {K.x, K.y, K.z, K.w};
#pragma unroll
        for (int jj = 0; jj < 4; ++jj) {
            float4 A = sA[j4 * 4 + jj];
            v2f ax = A.x, ay = A.y, az = A.z, ku = A.w, kv = kva[jj];
            // stage-interleaved: each stage does chain A then chain B, so
            // B's VALU can issue while A's trans op is in flight (and v.v.)
            v2f yA = VFMA(pxA, ax, VFMA(pyA, ay, az));
            v2f yB = VFMA(pxB, ax, VFMA(pyB, ay, az));
            v2f eA, eB;
            eA.x = __builtin_amdgcn_exp2f(yA.x);
            eB.x = __builtin_amdgcn_exp2f(yB.x);
            eA.y = __builtin_amdgcn_exp2f(yA.y);
            eB.y = __builtin_amdgcn_exp2f(yB.y);
            v2f dA = eA + one;
            v2f dB = eB + one;
            v2f rA, rB;
            rA.x = __builtin_amdgcn_rcpf(dA.x);
            rB.x = __builtin_amdgcn_rcpf(dB.x);
            rA.y = __builtin_amdgcn_rcpf(dA.y);
            rB.y = __builtin_amdgcn_rcpf(dB.y);
            v2f hA = VFMA(mtwo, rA, one);
            v2f hB = VFMA(mtwo, rB, one);
            v2f mA = VFMA(hA, hA, mone);
            v2f mB = VFMA(hB, hB, mone);
            v2f sA_ = hA * mA;
            v2f sB_ = hB * mB;
            uA = VFMA(sA_, ku, uA);
            uB = VFMA(sB_, ku, uB);
            vA = VFMA(sA_, kv, vA);
            vB = VFMA(sB_, kv, vB);
        }
    }

    out[base]           = make_float2(uA.x, vA.x);
    out[base + BLK]     = make_float2(uA.y, vA.y);
    out[base + 2 * BLK] = make_float2(uB.x, vB.x);
    out[base + 3 * BLK] = make_float2(uB.y, vB.y);
}

extern "C" void kernel_launch(void* const* d_in, const int* in_sizes, int n_in,
                              void* d_out, int out_size, void* d_ws, size_t ws_size,
                              hipStream_t stream) {
    // inputs: 0=f (unused), 1=xy, 2=W1, 3=b1, 4=W2, 5=b2 (unused by Hessian)
    const float* xy = (const float*)d_in[1];
    const float* W1 = (const float*)d_in[2];
    const float* b1 = (const float*)d_in[3];
    const float* W2 = (const float*)d_in[4];

    kDivFree_main<<<NPTS / (BLK * PPT), BLK, 0, stream>>>(
        (const float2*)xy, W1, b1, W2, (float2*)d_out);
}